// Round 1
// baseline (6514.133 us; speedup 1.0000x reference)
//
#include <hip/hip_runtime.h>
#include <math.h>

#define N 4096
#define NTHREADS 1024
#define ELEMS 4          // nodes per thread (4 * 1024 = 4096)
#define NWAVES (NTHREADS / 64)

__device__ __forceinline__ unsigned long long pack_key(float v, int idx) {
    // v >= 0 (distances / +INF), so float bit pattern is order-preserving.
    // Low 32 bits = index -> unsigned min gives (min value, then min index),
    // exactly matching jnp.argmin first-occurrence tie-breaking.
    unsigned int b = __float_as_uint(v);
    return ((unsigned long long)b << 32) | (unsigned int)idx;
}

// One block per matrix. Exact replication of the reference's vectorized Prim:
//   masked = where(in_tree, INF, min_dist); j = argmin(masked)  [lowest idx on tie]
//   in_tree[j] = True
//   better = (D[j] < min_dist) & ~in_tree   [strict <]
//   parent = where(better, j, parent); min_dist = where(better, D[j], min_dist)
// parent[k] freezes the moment k enters the tree, so the final parent array IS
// the (parent, child) pair list (child k != 0 appears exactly once).
__global__ __launch_bounds__(NTHREADS) void prim_kernel(const float* __restrict__ D1,
                                                        const float* __restrict__ D2,
                                                        int* __restrict__ parent_out_all) {
    const float* __restrict__ D = (blockIdx.x == 0) ? D1 : D2;
    int* __restrict__ parent_out = parent_out_all + (size_t)blockIdx.x * N;

    __shared__ unsigned long long red[NWAVES];
    __shared__ int sj;

    const int tid = threadIdx.x;
    const int base = tid * ELEMS;
    const int wid = tid >> 6;
    const int lane = tid & 63;
    const float INF = __builtin_inff();

    float md[ELEMS];
    int par[ELEMS];
    int mask = 0;  // in-tree bits for my 4 nodes

    // init: min_dist = D[0], parent = 0, in_tree = {0}
    float4 r0 = *(const float4*)(D + base);
    md[0] = r0.x; md[1] = r0.y; md[2] = r0.z; md[3] = r0.w;
#pragma unroll
    for (int e = 0; e < ELEMS; ++e) par[e] = 0;
    if (tid == 0) mask |= 1;  // node 0

    for (int step = 0; step < N - 1; ++step) {
        // --- thread-local masked argmin over my 4 nodes (first-index on tie) ---
        float bv = INF;
        int bi = N - 1;
#pragma unroll
        for (int e = 0; e < ELEMS; ++e) {
            float v = ((mask >> e) & 1) ? INF : md[e];
            if (v < bv) { bv = v; bi = base + e; }
        }
        unsigned long long key = pack_key(bv, bi);
        // --- 64-lane butterfly min ---
#pragma unroll
        for (int off = 32; off > 0; off >>= 1) {
            unsigned long long other = __shfl_xor(key, off, 64);
            if (other < key) key = other;
        }
        if (lane == 0) red[wid] = key;
        __syncthreads();
        if (tid == 0) {
            unsigned long long best = red[0];
#pragma unroll
            for (int w = 1; w < NWAVES; ++w)
                if (red[w] < best) best = red[w];
            sj = (int)(best & 0xffffffffULL);
        }
        __syncthreads();
        const int j = sj;

        // add j to tree BEFORE the update (matches reference order)
        if ((j >> 2) == tid) mask |= 1 << (j & 3);

        // --- read row j, relax ---
        float4 dj = *(const float4*)(D + (size_t)j * N + base);
        float dv[ELEMS] = {dj.x, dj.y, dj.z, dj.w};
#pragma unroll
        for (int e = 0; e < ELEMS; ++e) {
            if (!((mask >> e) & 1) && dv[e] < md[e]) {
                md[e] = dv[e];
                par[e] = j;
            }
        }
        // red[] reuse is safe: next iteration's writes happen after this
        // iteration's __syncthreads pair.
    }

    // dump parent array (par[k] frozen at insertion time for every k)
#pragma unroll
    for (int e = 0; e < ELEMS; ++e) parent_out[base + e] = par[e];
}

// distance1_2 = sqrt(sum_c (D1[p1[c],c] - D2[p1[c],c])^2)
// distance2_1 = sqrt(sum_c (D2[p2[c],c] - D1[p2[c],c])^2)
// matched     = sum_{c>=1} [p1[c] == p2[c]]
__global__ __launch_bounds__(1024) void finalize_kernel(const float* __restrict__ D1,
                                                        const float* __restrict__ D2,
                                                        const int* __restrict__ pw,
                                                        float* __restrict__ out) {
    __shared__ float rs12[16], rs21[16];
    __shared__ int rm[16];
    const int tid = threadIdx.x;
    const int* p1 = pw;
    const int* p2 = pw + N;

    float s12 = 0.f, s21 = 0.f;
    int m = 0;
    for (int c = 1 + tid; c < N; c += 1024) {
        int a = p1[c];
        int b = p2[c];
        float d1a = D1[(size_t)a * N + c];
        float d2a = D2[(size_t)a * N + c];
        float d2b = D2[(size_t)b * N + c];
        float d1b = D1[(size_t)b * N + c];
        float e1 = d1a - d2a;
        float e2 = d2b - d1b;
        s12 += e1 * e1;
        s21 += e2 * e2;
        m += (a == b) ? 1 : 0;
    }
#pragma unroll
    for (int off = 32; off > 0; off >>= 1) {
        s12 += __shfl_xor(s12, off, 64);
        s21 += __shfl_xor(s21, off, 64);
        m += __shfl_xor(m, off, 64);
    }
    const int wid = tid >> 6, lane = tid & 63;
    if (lane == 0) { rs12[wid] = s12; rs21[wid] = s21; rm[wid] = m; }
    __syncthreads();
    if (tid == 0) {
        float a = 0.f, b = 0.f;
        int mm = 0;
#pragma unroll
        for (int w = 0; w < 16; ++w) { a += rs12[w]; b += rs21[w]; mm += rm[w]; }
        float d12 = sqrtf(a);
        float d21 = sqrtf(b);
        out[0] = d12 + d21;
        out[1] = d12;
        out[2] = d21;
        out[3] = (float)mm;
    }
}

extern "C" void kernel_launch(void* const* d_in, const int* in_sizes, int n_in,
                              void* d_out, int out_size, void* d_ws, size_t ws_size,
                              hipStream_t stream) {
    const float* D1 = (const float*)d_in[0];
    const float* D2 = (const float*)d_in[1];
    int* pw = (int*)d_ws;  // 2*N ints = 32 KB

    // Both matrices' Prim runs in one launch (2 blocks, concurrent CUs).
    prim_kernel<<<2, NTHREADS, 0, stream>>>(D1, D2, pw);
    finalize_kernel<<<1, 1024, 0, stream>>>(D1, D2, pw, (float*)d_out);
}

// Round 2
// 460.102 us; speedup vs baseline: 14.1580x; 14.1580x over previous
//
#include <hip/hip_runtime.h>
#include <math.h>

#define N 4096
#define ROUNDS 12           // components at least halve per round: 4096 -> 1 guaranteed
#define INFKEY 0xFFFFFFFFFFFFFFFFULL
#define ROWS_PER_BLOCK 16   // 16 waves * 1 row each, 1024 threads

// ---- workspace layout (bytes) ----
// cand   : u64[2*N]   @ 0        (65536)
// comp   : int[2*N]   @ 65536    (32768)
// edges  : int2[2*N]  @ 98304    (65536)   4096 slots per matrix, 4095 used
// parent : int[2*N]   @ 163840   (32768)   (reused as link scratch during rounds)
// meta   : int[4]     @ 196608   done0, done1, ecnt0, ecnt1
#define WS_CAND(ws)   ((unsigned long long*)((char*)(ws) + 0))
#define WS_COMP(ws)   ((int*)((char*)(ws) + 65536))
#define WS_EDGES(ws)  ((int2*)((char*)(ws) + 98304))
#define WS_PARENT(ws) ((int*)((char*)(ws) + 163840))
#define WS_META(ws)   ((int*)((char*)(ws) + 196608))

// key packing: (float_bits(w) << 24) | (u << 12) | v   -- 56 bits, u64 atomicMin
// distances >= 0 so float bit pattern is order-preserving; unique weights assumed
// (fp32 Gaussian data), deterministic (u,v) tiebreak otherwise.

__global__ void init_kernel(int* comp, unsigned long long* cand, int* meta) {
    int i = blockIdx.x * 256 + threadIdx.x;
    if (i < 2 * N) {
        comp[i] = i & (N - 1);
        cand[i] = INFKEY;
    }
    if (i < 4) meta[i] = 0;
}

// One wave per row: min over j of D[row][j] with comp[j] != comp[row].
// Full 64 MB stream per matrix per round; comp staged in LDS.
__global__ __launch_bounds__(1024) void boruvka_scan(const float* __restrict__ D1,
                                                     const float* __restrict__ D2,
                                                     const int* __restrict__ comp,
                                                     unsigned long long* __restrict__ cand,
                                                     const int* __restrict__ meta) {
    const int blocks_per_mat = N / ROWS_PER_BLOCK;  // 256
    const int m = (blockIdx.x >= blocks_per_mat) ? 1 : 0;
    if (meta[m]) return;  // this matrix's MST is complete
    const float* __restrict__ D = m ? D2 : D1;
    const int* __restrict__ cm = comp + m * N;
    unsigned long long* __restrict__ cd = cand + m * N;

    __shared__ int scomp[N];
    const int tid = threadIdx.x;
    for (int i = tid; i < N / 4; i += 1024)
        ((int4*)scomp)[i] = ((const int4*)cm)[i];
    __syncthreads();

    const int wid = tid >> 6, lane = tid & 63;
    const int row = (blockIdx.x - m * blocks_per_mat) * ROWS_PER_BLOCK + wid;
    const int ci = scomp[row];
    const float* __restrict__ Drow = D + (size_t)row * N;

    unsigned long long best = INFKEY;
    for (int j0 = lane * 4; j0 < N; j0 += 256) {
        float4 d = *(const float4*)(Drow + j0);
        int4 cj = *(const int4*)(scomp + j0);
        if (cj.x != ci) {
            unsigned long long k = ((unsigned long long)__float_as_uint(d.x) << 24) | (unsigned)(j0 + 0);
            if (k < best) best = k;
        }
        if (cj.y != ci) {
            unsigned long long k = ((unsigned long long)__float_as_uint(d.y) << 24) | (unsigned)(j0 + 1);
            if (k < best) best = k;
        }
        if (cj.z != ci) {
            unsigned long long k = ((unsigned long long)__float_as_uint(d.z) << 24) | (unsigned)(j0 + 2);
            if (k < best) best = k;
        }
        if (cj.w != ci) {
            unsigned long long k = ((unsigned long long)__float_as_uint(d.w) << 24) | (unsigned)(j0 + 3);
            if (k < best) best = k;
        }
    }
#pragma unroll
    for (int off = 32; off > 0; off >>= 1) {
        unsigned long long o = __shfl_xor(best, off, 64);
        if (o < best) best = o;
    }
    if (lane == 0 && best != INFKEY)
        atomicMin(&cd[ci], best | ((unsigned long long)row << 12));
}

// One workgroup per matrix: hook components along their min edges (mutual pair ->
// lower index stays root), record MST edges, pointer-jump compress labels,
// detect completion, re-init cand.
__global__ __launch_bounds__(1024) void boruvka_hook(int* __restrict__ comp,
                                                     unsigned long long* __restrict__ cand,
                                                     int* __restrict__ link,
                                                     int2* __restrict__ edges,
                                                     int* __restrict__ meta) {
    const int m = blockIdx.x;
    if (meta[m]) return;
    int* __restrict__ cm = comp + m * N;
    unsigned long long* __restrict__ cd = cand + m * N;
    int* __restrict__ lk = link + m * N;   // parent array reused as scratch
    int2* __restrict__ ed = edges + m * N;
    int* __restrict__ ecnt = meta + 2 + m;
    const int tid = threadIdx.x;

    // pass 1: per-root decision, written to lk (comp stays pre-hook-consistent)
    for (int c = tid; c < N; c += 1024) {
        int l = cm[c];
        if (l == c) {  // root
            unsigned long long k = cd[c];
            if (k != INFKEY) {
                int v = (int)(k & 0xFFF);
                int u = (int)((k >> 12) & 0xFFF);
                int t = cm[v];  // target root (labels fully compressed)
                unsigned long long tk = cd[t];
                int mutual = 0;
                if (tk != INFKEY) {
                    int tv = (int)(tk & 0xFFF);
                    mutual = (cm[tv] == c);
                }
                if (mutual) {
                    if (c < t) {  // winner stays root, records the shared min edge
                        int idx = atomicAdd(ecnt, 1);
                        ed[idx] = make_int2(u, v);
                    } else {      // loser hooks, no record (winner recorded it)
                        l = t;
                    }
                } else {          // chain hook: record own min edge
                    int idx = atomicAdd(ecnt, 1);
                    ed[idx] = make_int2(u, v);
                    l = t;
                }
            }
        }
        lk[c] = l;
    }
    __syncthreads();
    for (int c = tid; c < N; c += 1024) cm[c] = lk[c];
    __syncthreads();

    // pointer jumping: chains are <= #components long; 12 synced passes suffice
    for (int it = 0; it < 12; ++it) {
        for (int c = tid; c < N; c += 1024) cm[c] = cm[cm[c]];
        __syncthreads();
    }

    // completion check
    __shared__ int cnt;
    if (tid == 0) cnt = 0;
    __syncthreads();
    int local = 0;
    for (int c = tid; c < N; c += 1024) local += (cm[c] == c) ? 1 : 0;
    atomicAdd(&cnt, local);
    __syncthreads();
    if (tid == 0 && cnt == 1) meta[m] = 1;

    // re-init candidates for next round
    for (int c = tid; c < N; c += 1024) cd[c] = INFKEY;
}

// One workgroup per matrix: orient the N-1 undirected MST edges toward root 0.
// Level-synchronous (double-buffered known flags) so each pass only propagates
// from the consistent frontier -> at most one known neighbor per unknown node
// -> race-free single writer per parent slot.
__global__ __launch_bounds__(1024) void root_kernel(const int2* __restrict__ edges,
                                                    const int* __restrict__ meta,
                                                    int* __restrict__ parent) {
    const int m = blockIdx.x;
    const int2* __restrict__ ed = edges + m * N;
    int* __restrict__ p = parent + m * N;
    const int ec = meta[2 + m];  // == N-1

    __shared__ int2 se[N];
    __shared__ int sp[N];
    __shared__ unsigned char kprev[N], kcur[N];
    __shared__ int changed;
    const int tid = threadIdx.x;

    for (int i = tid; i < ec; i += 1024) se[i] = ed[i];
    for (int i = tid; i < N; i += 1024) {
        sp[i] = 0;
        kprev[i] = 0;
        kcur[i] = 0;
    }
    __syncthreads();
    if (tid == 0) { kprev[0] = 1; kcur[0] = 1; }
    __syncthreads();

    for (int pass = 0; pass < N; ++pass) {
        if (tid == 0) changed = 0;
        __syncthreads();
        for (int e = tid; e < ec; e += 1024) {
            int2 uv = se[e];
            unsigned char ku = kprev[uv.x], kv = kprev[uv.y];
            if (ku && !kv) { sp[uv.y] = uv.x; kcur[uv.y] = 1; changed = 1; }
            else if (kv && !ku) { sp[uv.x] = uv.y; kcur[uv.x] = 1; changed = 1; }
        }
        __syncthreads();
        int go = changed;
        __syncthreads();
        if (!go) break;
        for (int i = tid; i < N; i += 1024) kprev[i] = kcur[i];
        __syncthreads();
    }

    for (int i = tid; i < N; i += 1024) p[i] = sp[i];
}

// distance1_2 = sqrt(sum_c (D1[p1[c],c] - D2[p1[c],c])^2), etc.
// matched = sum_{c>=1} [p1[c]==p2[c]]  (child row uniquely identifies the pair)
__global__ __launch_bounds__(1024) void finalize_kernel(const float* __restrict__ D1,
                                                        const float* __restrict__ D2,
                                                        const int* __restrict__ parent,
                                                        float* __restrict__ out) {
    __shared__ float rs12[16], rs21[16];
    __shared__ int rm[16];
    const int tid = threadIdx.x;
    const int* p1 = parent;
    const int* p2 = parent + N;

    float s12 = 0.f, s21 = 0.f;
    int mcnt = 0;
    for (int c = 1 + tid; c < N; c += 1024) {
        int a = p1[c];
        int b = p2[c];
        float e1 = D1[(size_t)a * N + c] - D2[(size_t)a * N + c];
        float e2 = D2[(size_t)b * N + c] - D1[(size_t)b * N + c];
        s12 += e1 * e1;
        s21 += e2 * e2;
        mcnt += (a == b) ? 1 : 0;
    }
#pragma unroll
    for (int off = 32; off > 0; off >>= 1) {
        s12 += __shfl_xor(s12, off, 64);
        s21 += __shfl_xor(s21, off, 64);
        mcnt += __shfl_xor(mcnt, off, 64);
    }
    const int wid = tid >> 6, lane = tid & 63;
    if (lane == 0) { rs12[wid] = s12; rs21[wid] = s21; rm[wid] = mcnt; }
    __syncthreads();
    if (tid == 0) {
        float a = 0.f, b = 0.f;
        int mm = 0;
#pragma unroll
        for (int w = 0; w < 16; ++w) { a += rs12[w]; b += rs21[w]; mm += rm[w]; }
        float d12 = sqrtf(a);
        float d21 = sqrtf(b);
        out[0] = d12 + d21;
        out[1] = d12;
        out[2] = d21;
        out[3] = (float)mm;
    }
}

extern "C" void kernel_launch(void* const* d_in, const int* in_sizes, int n_in,
                              void* d_out, int out_size, void* d_ws, size_t ws_size,
                              hipStream_t stream) {
    const float* D1 = (const float*)d_in[0];
    const float* D2 = (const float*)d_in[1];

    unsigned long long* cand = WS_CAND(d_ws);
    int* comp = WS_COMP(d_ws);
    int2* edges = WS_EDGES(d_ws);
    int* parent = WS_PARENT(d_ws);
    int* meta = WS_META(d_ws);

    init_kernel<<<(2 * N + 255) / 256, 256, 0, stream>>>(comp, cand, meta);

    const int scan_grid = 2 * (N / ROWS_PER_BLOCK);  // 512 blocks, both matrices
    for (int r = 0; r < ROUNDS; ++r) {
        boruvka_scan<<<scan_grid, 1024, 0, stream>>>(D1, D2, comp, cand, meta);
        boruvka_hook<<<2, 1024, 0, stream>>>(comp, cand, parent, edges, meta);
    }

    root_kernel<<<2, 1024, 0, stream>>>(edges, meta, parent);
    finalize_kernel<<<1, 1024, 0, stream>>>(D1, D2, parent, (float*)d_out);
}